// Round 1
// 263.662 us; speedup vs baseline: 1.1433x; 1.1433x over previous
//
#include <hip/hip_runtime.h>
#include <hip/hip_fp16.h>

#define DD 128
#define GG 256
#define RANGES 4
#define RSMAX 12544
#define NCHUNK 64

typedef _Float16 half8 __attribute__((ext_vector_type(8)));
typedef float floatx4 __attribute__((ext_vector_type(4)));

__device__ inline uint2 pack_half4(float4 v) {
    __half2 a = __floats2half2_rn(v.x, v.y);
    __half2 b = __floats2half2_rn(v.z, v.w);
    uint2 u;
    u.x = *reinterpret_cast<unsigned int*>(&a);
    u.y = *reinterpret_cast<unsigned int*>(&b);
    return u;
}

// key[e] = src | (dst << 16)   (N < 65536)
__global__ __launch_bounds__(256) void k_key(const int* __restrict__ src, const int* __restrict__ dst,
                                             unsigned int* __restrict__ key, int E) {
    int i = (blockIdx.x * 256 + threadIdx.x) * 4;
    if (i + 3 < E) {
        int4 s4 = *(const int4*)&src[i];
        int4 d4 = *(const int4*)&dst[i];
        uint4 k4;
        k4.x = (unsigned int)s4.x | ((unsigned int)d4.x << 16);
        k4.y = (unsigned int)s4.y | ((unsigned int)d4.y << 16);
        k4.z = (unsigned int)s4.z | ((unsigned int)d4.z << 16);
        k4.w = (unsigned int)s4.w | ((unsigned int)d4.w << 16);
        *(uint4*)&key[i] = k4;
    } else {
        for (int j = 0; j < 4 && i + j < E; ++j)
            key[i + j] = (unsigned int)src[i + j] | ((unsigned int)dst[i + j] << 16);
    }
}

// ---------------- packed-u16 LDS histogram: h[n] = deg_out | deg_in<<16 ----------------
__global__ __launch_bounds__(256) void k_hist2(const unsigned int* __restrict__ key,
                                               unsigned int* __restrict__ pk,
                                               int E, int N, int C, int RS, int L) {
    __shared__ unsigned int h[RSMAX];
    int r = blockIdx.x / C;
    int c = blockIdx.x % C;
    int r0 = r * RS;
    int r1 = min(r0 + RS, N);
    int nb = r1 - r0;
    for (int i = threadIdx.x; i < nb; i += 256) h[i] = 0;
    __syncthreads();
    int e0 = c * L, e1 = min(e0 + L, E);
    for (int e = e0 + threadIdx.x * 4; e < e1; e += 1024) {
        if (e + 3 < e1) {
            uint4 k4 = *(const uint4*)&key[e];
            #pragma unroll
            for (int j = 0; j < 4; ++j) {
                unsigned int kk = (j == 0) ? k4.x : (j == 1) ? k4.y : (j == 2) ? k4.z : k4.w;
                int s = (int)(kk & 0xFFFFu);
                int d = (int)(kk >> 16);
                if (s >= r0 && s < r1) atomicAdd(&h[s - r0], 1u);
                if (d >= r0 && d < r1) atomicAdd(&h[d - r0], 65536u);
            }
        } else {
            for (int j = 0; j < 4 && e + j < e1; ++j) {
                unsigned int kk = key[e + j];
                int s = (int)(kk & 0xFFFFu);
                int d = (int)(kk >> 16);
                if (s >= r0 && s < r1) atomicAdd(&h[s - r0], 1u);
                if (d >= r0 && d < r1) atomicAdd(&h[d - r0], 65536u);
            }
        }
    }
    __syncthreads();
    for (int i = threadIdx.x; i < nb; i += 256)
        pk[(size_t)c * N + r0 + i] = h[i];
}

// reduce packed partials -> norms, deg_in, and per-256-chunk block sums (fused scan_a)
__global__ __launch_bounds__(256) void k_reduce(const unsigned int* __restrict__ pk,
                                                float* __restrict__ norm_out, float* __restrict__ norm_in,
                                                int* __restrict__ deg_in, int* __restrict__ bsum,
                                                int N, int C) {
    __shared__ int ws[4];
    int n = blockIdx.x * 256 + threadIdx.x;
    int so = 0, si = 0;
    if (n < N) {
        for (int c = 0; c < C; ++c) {
            unsigned int v = pk[(size_t)c * N + n];
            so += (int)(v & 0xFFFFu);
            si += (int)(v >> 16);
        }
        norm_out[n] = rsqrtf(fmaxf((float)so, 1.0f));
        norm_in[n] = rsqrtf(fmaxf((float)si, 1.0f));
        deg_in[n] = si;
    }
    int s = si;
    #pragma unroll
    for (int off = 32; off; off >>= 1) s += __shfl_xor(s, off);
    int lane = threadIdx.x & 63, w = threadIdx.x >> 6;
    if (lane == 0) ws[w] = s;
    __syncthreads();
    if (threadIdx.x == 0) bsum[blockIdx.x] = ws[0] + ws[1] + ws[2] + ws[3];
}

// multi-role kernel: block 0 = scan_b over bsum; blocks 1-2 = gstart; blocks 3..194 = wconv;
// blocks 195.. = scale (feats * norm_out -> half Xh).
__global__ __launch_bounds__(256) void k_misc(int* bsum, int nblk, int* row_ptr, int N,
                                              const int* __restrict__ gid, int* g_start, int G,
                                              const float* __restrict__ W, __half* __restrict__ Wt,
                                              const float* __restrict__ feats,
                                              const float* __restrict__ norm_out,
                                              uint2* __restrict__ Xh) {
    int blk = blockIdx.x;
    int tid = threadIdx.x;
    if (blk == 0) {
        if (tid < 64) {
            int lane = tid;
            int carry = 0;
            for (int base = 0; base < nblk; base += 64) {
                int i = base + lane;
                int v = (i < nblk) ? bsum[i] : 0;
                int s = v;
                #pragma unroll
                for (int off = 1; off < 64; off <<= 1) {
                    int u = __shfl_up(s, off);
                    if (lane >= off) s += u;
                }
                if (i < nblk) bsum[i] = carry + s - v;
                carry += __shfl(s, 63);
            }
            if (lane == 0) row_ptr[N] = carry;
        }
    } else if (blk <= 2) {
        int g = (blk - 1) * 256 + tid;
        if (g <= G) {
            int lo = 0, hi = N;
            while (lo < hi) {
                int mid = (lo + hi) >> 1;
                if (gid[mid] < g) lo = mid + 1; else hi = mid;
            }
            g_start[g] = lo;
        }
    } else if (blk <= 194) {
        int i = (blk - 3) * 256 + tid;
        if (i < 3 * 16384) {
            int l = i >> 14;
            int rem = i & 16383;
            int n = rem >> 7;
            int k = rem & 127;
            Wt[(size_t)l * 16384 + n * 128 + k] = __float2half(W[(size_t)l * 16384 + k * 128 + n]);
        }
    } else {
        int i = (blk - 195) * 256 + tid;
        if (i < N * 32) {
            int n = i >> 5;
            float4 v = ((const float4*)feats)[i];
            float s = norm_out[n];
            v.x *= s; v.y *= s; v.z *= s; v.w *= s;
            Xh[i] = pack_half4(v);
        }
    }
}

// exclusive scan over 256-node chunks + fused per-chunk fill base + zero pooled output
__global__ __launch_bounds__(256) void k_scan_cb(const int* __restrict__ deg, const int* __restrict__ bsum,
                                                 const unsigned int* __restrict__ pk,
                                                 int* __restrict__ row_ptr, int* __restrict__ fbase,
                                                 float* __restrict__ pool0,
                                                 int N, int C) {
    __shared__ int ws[4];
    int t = threadIdx.x;
    if (blockIdx.x < 32) {
        // zero the [GG][DD] pooled output (32 blocks x 256 threads x 16B = 128 KiB)
        float4 z = make_float4(0.f, 0.f, 0.f, 0.f);
        ((float4*)pool0)[blockIdx.x * 256 + t] = z;
    }
    int n = blockIdx.x * 256 + t;
    int v = (n < N) ? deg[n] : 0;
    int lane = t & 63, w = t >> 6;
    int incl = v;
    #pragma unroll
    for (int off = 1; off < 64; off <<= 1) {
        int u = __shfl_up(incl, off);
        if (lane >= off) incl += u;
    }
    if (lane == 63) ws[w] = incl;
    __syncthreads();
    int woff = 0;
    for (int j = 0; j < w; ++j) woff += ws[j];
    if (n < N) {
        int run = bsum[blockIdx.x] + woff + incl - v;
        row_ptr[n] = run;
        for (int c = 0; c < C; ++c) {
            int h = (int)(pk[(size_t)c * N + n] >> 16);
            fbase[(size_t)c * N + n] = run;
            run += h;
        }
    }
}

// fill CSR from key: int LDS slot counters seeded from per-chunk base
__global__ __launch_bounds__(256) void k_fill2(const unsigned int* __restrict__ key,
                                               const int* __restrict__ base, int* __restrict__ col_src,
                                               int E, int N, int C, int RS, int L) {
    __shared__ int cnt[RSMAX];
    int r = blockIdx.x / C;
    int c = blockIdx.x % C;
    int r0 = r * RS;
    int r1 = min(r0 + RS, N);
    int nb = r1 - r0;
    const int* bc = base + (size_t)c * N;
    for (int i = threadIdx.x; i < nb; i += 256) cnt[i] = bc[r0 + i];
    __syncthreads();
    int e0 = c * L, e1 = min(e0 + L, E);
    for (int e = e0 + threadIdx.x * 4; e < e1; e += 1024) {
        if (e + 3 < e1) {
            uint4 k4 = *(const uint4*)&key[e];
            #pragma unroll
            for (int j = 0; j < 4; ++j) {
                unsigned int kk = (j == 0) ? k4.x : (j == 1) ? k4.y : (j == 2) ? k4.z : k4.w;
                int s = (int)(kk & 0xFFFFu);
                int d = (int)(kk >> 16);
                if (d >= r0 && d < r1) { int o = atomicAdd(&cnt[d - r0], 1); col_src[o] = s; }
            }
        } else {
            for (int j = 0; j < 4 && e + j < e1; ++j) {
                unsigned int kk = key[e + j];
                int s = (int)(kk & 0xFFFFu);
                int d = (int)(kk >> 16);
                if (d >= r0 && d < r1) { int o = atomicAdd(&cnt[d - r0], 1); col_src[o] = s; }
            }
        }
    }
}

__device__ inline void acc_row(float* acc, uint4 u) {
    const __half2* h = (const __half2*)&u;
    #pragma unroll
    for (int i = 0; i < 4; ++i) {
        float2 f = __half22float2(h[i]);
        acc[2 * i] += f.x;
        acc[2 * i + 1] += f.y;
    }
}

// FUSED: pull-mode aggregation (16 lanes/node, 16 nodes/block, identical memory
// pattern to old k_agg) -> 16x128 LDS A-tile -> MFMA x W -> epilogue.
// Layers 0/1: Xout[node] = half(relu(agg@W + b) * norm_out)   (ping-pong buffers)
// Layer  2 : pooled atomic readout into out[G][128] (block-uniform-graph fast path)
__global__ __launch_bounds__(256, 8) void k_agg_mm(
    const uint4* __restrict__ Xin, const float* __restrict__ norm_in,
    const int* __restrict__ row_ptr, const int* __restrict__ col_src,
    const __half* __restrict__ Wt, const float* __restrict__ bl,
    const float* __restrict__ scale, __half* __restrict__ Xout,
    float* __restrict__ pool_out, const int* __restrict__ gid,
    const int* __restrict__ g_start, int N) {
    __shared__ _Float16 Ah[16 * 136];
    int t = threadIdx.x;
    int n0 = blockIdx.x * 16;
    int l16 = t & 15;
    int grp = t >> 4;
    int n = n0 + grp;

    // ---- gather phase (same structure/occupancy as old k_agg) ----
    float acc[8] = {};
    if (n < N) {
        int beg = row_ptr[n], end = row_ptr[n + 1];
        int k = beg;
        bool have = (k + 3 < end);
        int4 s = make_int4(0, 0, 0, 0);
        if (have) s = *(const int4*)&col_src[k];
        while (have) {
            int kn = k + 4;
            bool haven = (kn + 3 < end);
            int4 sn = s;
            if (haven) sn = *(const int4*)&col_src[kn];
            uint4 u0 = Xin[(size_t)s.x * 16 + l16];
            uint4 u1 = Xin[(size_t)s.y * 16 + l16];
            uint4 u2 = Xin[(size_t)s.z * 16 + l16];
            uint4 u3 = Xin[(size_t)s.w * 16 + l16];
            acc_row(acc, u0);
            acc_row(acc, u1);
            acc_row(acc, u2);
            acc_row(acc, u3);
            s = sn; k = kn; have = haven;
        }
        for (; k < end; ++k) {
            uint4 u = Xin[(size_t)col_src[k] * 16 + l16];
            acc_row(acc, u);
        }
        float ni = norm_in[n];
        #pragma unroll
        for (int i = 0; i < 8; ++i) acc[i] *= ni;
    }
    __half2 hp[4];
    #pragma unroll
    for (int i = 0; i < 4; ++i) hp[i] = __floats2half2_rn(acc[2 * i], acc[2 * i + 1]);
    *(uint4*)&Ah[grp * 136 + l16 * 8] = *(const uint4*)hp;
    __syncthreads();

    // ---- MFMA phase: 16 rows x 128 cols; wave w covers cols [w*32, w*32+32) ----
    int wave = t >> 6;
    int lane = t & 63;
    int quad = lane >> 4;
    int mrow = lane & 15;

    half8 af[4];
    #pragma unroll
    for (int kc = 0; kc < 4; ++kc)
        af[kc] = *(const half8*)&Ah[mrow * 136 + kc * 32 + quad * 8];

    floatx4 Cc[2];
    Cc[0] = (floatx4){0.f, 0.f, 0.f, 0.f};
    Cc[1] = (floatx4){0.f, 0.f, 0.f, 0.f};
    #pragma unroll
    for (int ct = 0; ct < 2; ++ct) {
        int col = wave * 32 + ct * 16 + mrow;
        #pragma unroll
        for (int kc = 0; kc < 4; ++kc) {
            half8 bf = *(const half8*)&Wt[(size_t)col * 128 + kc * 32 + quad * 8];
            Cc[ct] = __builtin_amdgcn_mfma_f32_16x16x32_f16(af[kc], bf, Cc[ct], 0, 0, 0);
        }
    }

    if (Xout) {
        float sc[4];
        #pragma unroll
        for (int r = 0; r < 4; ++r) {
            int node = n0 + quad * 4 + r;
            sc[r] = (node < N) ? scale[node] : 1.0f;
        }
        #pragma unroll
        for (int ct = 0; ct < 2; ++ct) {
            int col = wave * 32 + ct * 16 + mrow;
            float bias = bl[col];
            #pragma unroll
            for (int r = 0; r < 4; ++r) {
                int node = n0 + quad * 4 + r;
                if (node < N)
                    Xout[(size_t)node * 128 + col] =
                        __float2half(fmaxf(Cc[ct][r] + bias, 0.f) * sc[r]);
            }
        }
    } else {
        // pooled readout: nodes sorted by graph id -> tile is usually graph-uniform
        int nlast = min(n0 + 15, N - 1);
        int ga = (n0 < N) ? gid[n0] : -1;
        int gb = (n0 < N) ? gid[nlast] : -2;
        if (ga == gb && ga >= 0) {
            float inv = 1.f / fmaxf((float)(g_start[ga + 1] - g_start[ga]), 1.f);
            #pragma unroll
            for (int ct = 0; ct < 2; ++ct) {
                int col = wave * 32 + ct * 16 + mrow;
                float bias = bl[col];
                float s = 0.f;
                #pragma unroll
                for (int r = 0; r < 4; ++r) {
                    int node = n0 + quad * 4 + r;
                    if (node < N) s += fmaxf(Cc[ct][r] + bias, 0.f);
                }
                s += __shfl_xor(s, 16);
                s += __shfl_xor(s, 32);
                if (quad == 0) atomicAdd(&pool_out[(size_t)ga * DD + col], s * inv);
            }
        } else {
            int garr[4];
            #pragma unroll
            for (int r = 0; r < 4; ++r) {
                int node = n0 + quad * 4 + r;
                garr[r] = (node < N) ? gid[node] : -1;
            }
            #pragma unroll
            for (int ct = 0; ct < 2; ++ct) {
                int col = wave * 32 + ct * 16 + mrow;
                float bias = bl[col];
                float s = 0.f;
                int gcur = -1;
                #pragma unroll
                for (int r = 0; r < 4; ++r) {
                    if (garr[r] >= 0) {
                        float val = fmaxf(Cc[ct][r] + bias, 0.f);
                        if (garr[r] != gcur) {
                            if (gcur >= 0) {
                                float cnt = fmaxf((float)(g_start[gcur + 1] - g_start[gcur]), 1.f);
                                atomicAdd(&pool_out[(size_t)gcur * DD + col], s / cnt);
                            }
                            gcur = garr[r];
                            s = 0.f;
                        }
                        s += val;
                    }
                }
                if (gcur >= 0) {
                    float cnt = fmaxf((float)(g_start[gcur + 1] - g_start[gcur]), 1.f);
                    atomicAdd(&pool_out[(size_t)gcur * DD + col], s / cnt);
                }
            }
        }
    }
}

extern "C" void kernel_launch(void* const* d_in, const int* in_sizes, int n_in,
                              void* d_out, int out_size, void* d_ws, size_t ws_size,
                              hipStream_t stream) {
    const float* feats = (const float*)d_in[0];
    const float* W = (const float*)d_in[1];
    const float* b = (const float*)d_in[2];
    const int* src = (const int*)d_in[3];
    const int* dst = (const int*)d_in[4];
    const int* gid = (const int*)d_in[5];
    float* out = (float*)d_out;
    const int N = in_sizes[0] / DD;  // 50000
    const int E = in_sizes[3];       // 800000

    const int C = NCHUNK;                        // 64
    const int RS = (N + RANGES - 1) / RANGES;    // 12500 <= RSMAX
    const int L = (((E + C - 1) / C) + 3) & ~3;  // 12500

    char* ws = (char*)d_ws;
    size_t off = 0;
    auto take = [&](size_t bytes) {
        char* p = ws + off;
        off = (off + bytes + 255) & ~(size_t)255;
        return p;
    };
    float* norm_out = (float*)take((size_t)N * 4);
    float* norm_in  = (float*)take((size_t)N * 4);
    int*   deg_in   = (int*)take((size_t)N * 4);
    int*   row_ptr  = (int*)take((size_t)(N + 1) * 4);
    int*   col_src  = (int*)take((size_t)E * 4);
    int*   g_start  = (int*)take((size_t)(GG + 1) * 4);
    int*   bsum     = (int*)take((size_t)1024 * 4);
    unsigned int* key = (unsigned int*)take((size_t)E * 4);
    __half* Wth     = (__half*)take((size_t)3 * 16384 * 2);
    uint4* Xh       = (uint4*)take((size_t)N * DD * 2);   // half features (ping)
    uint4* Yh       = (uint4*)take((size_t)N * DD * 2);   // half features (pong)
    size_t chunk_arr = ((size_t)C * N * 4 + 255) & ~(size_t)255;   // 12.8 MB
    char* uni = take(2 * chunk_arr);
    unsigned int* pk = (unsigned int*)uni;
    int* fbase = (int*)(uni + chunk_arr);

    const int nblk = (N + 255) / 256;  // 196 reduce/scan chunks
    const int mgrid_misc = 195 + (N * 32 + 255) / 256;

    k_key<<<(E + 1023) / 1024, 256, 0, stream>>>(src, dst, key, E);
    k_hist2<<<RANGES * C, 256, 0, stream>>>(key, pk, E, N, C, RS, L);
    k_reduce<<<nblk, 256, 0, stream>>>(pk, norm_out, norm_in, deg_in, bsum, N, C);
    k_misc<<<mgrid_misc, 256, 0, stream>>>(bsum, nblk, row_ptr, N, gid, g_start, GG,
                                           W, Wth, feats, norm_out, (uint2*)Xh);
    k_scan_cb<<<nblk, 256, 0, stream>>>(deg_in, bsum, pk, row_ptr, fbase, out, N, C);
    k_fill2<<<RANGES * C, 256, 0, stream>>>(key, fbase, col_src, E, N, C, RS, L);

    const int agrid = (N + 15) / 16;  // 3125
    for (int l = 0; l < 3; ++l) {
        const __half* Wtl = Wth + (size_t)l * 16384;
        const float* blp = b + (size_t)l * DD;
        const uint4* Xi = (l == 1) ? Yh : Xh;      // l0:Xh -> Yh ; l1:Yh -> Xh ; l2:Xh -> pooled
        if (l < 2) {
            __half* Xo = (__half*)((l == 0) ? Yh : Xh);
            k_agg_mm<<<agrid, 256, 0, stream>>>(Xi, norm_in, row_ptr, col_src, Wtl, blp,
                                                norm_out, Xo, nullptr, nullptr, nullptr, N);
        } else {
            k_agg_mm<<<agrid, 256, 0, stream>>>(Xi, norm_in, row_ptr, col_src, Wtl, blp,
                                                nullptr, nullptr, out, gid, g_start, N);
        }
    }
}